// Round 13
// baseline (335.123 us; speedup 1.0000x reference)
//
#include <hip/hip_runtime.h>
#include <math.h>

#define N_NODES 10000
#define FEAT 512
#define HID 256
#define EMB 128
#define NC 10
#define NE_EDGES 160000
#define KTOP 10
#define NNB 9

#define CAP 128          // per-row candidate buffer capacity
#define NSEL 24          // candidates f64-rescored (fp8 phase-1 -> wider margin)
#define TAU 0.11f        // store threshold (sims ~ N(0,0.0442), s10 ~ 0.19)
#define SAFE_VAL 0.12f   // need >=10 stored above this, else fallback
#define NTB 79           // 79 tiles of 128 (feature GEMMs)
#define NTB2 40          // 40 tiles of 256 (sim GEMM)
#define NPAIR2 820       // 40*41/2 upper-triangle blocks
#define QCAP2 8192       // per-block LDS hit queue (48KB region; expected ~420 hits)

typedef __attribute__((ext_vector_type(8))) short short8;
typedef __attribute__((ext_vector_type(4))) float f32x4;

typedef const __attribute__((address_space(1))) unsigned int* gas1_t;
typedef __attribute__((address_space(3))) unsigned int* las3_t;

__device__ __forceinline__ void gload_lds16(const void* g, void* l) {
  __builtin_amdgcn_global_load_lds((gas1_t)g, (las3_t)l, 16, 0, 0);
}

__device__ __forceinline__ unsigned short f2h(float f) {
  _Float16 h = (_Float16)f;
  return *(unsigned short*)&h;
}
__device__ __forceinline__ float h2f(unsigned short u) {
  _Float16 h = *(_Float16*)&u;
  return (float)h;
}

// f32 -> OCP e4m3fn, RNE (inputs |x| <= 1 here; no inf/nan cases)
__device__ __forceinline__ unsigned char f2e8(float f) {
  const unsigned u = __float_as_uint(f);
  const unsigned sg = (u >> 24) & 0x80u;
  const int e = (int)((u >> 23) & 0xffu) - 127;
  const unsigned m = u & 0x7fffffu;
  if (e >= -6) {
    if (e > 8) return sg | 0x7eu;
    unsigned mant = m >> 20;
    const unsigned rest = m & 0xfffffu;
    if (rest > 0x80000u || (rest == 0x80000u && (mant & 1u))) ++mant;
    unsigned ex = (unsigned)(e + 7);
    if (mant == 8u) { mant = 0u; ++ex; }
    if (ex > 15u || (ex == 15u && mant == 7u)) return sg | 0x7eu;
    return sg | (ex << 3) | mant;
  }
  const float af = fabsf(f);
  const int q = (int)(af * 512.0f + 0.5f);
  if (q > 7) return sg | 0x08u;
  return sg | (unsigned)q;
}

// ---- row norms -> K-blocked fp8 normalized (xn8[kb][node][64]) + f16 raw + f64 inv norms ----
__global__ void k_norms(const float* __restrict__ x, unsigned char* __restrict__ xn8,
                        unsigned short* __restrict__ xf, double* __restrict__ rinv) {
  const int row = blockIdx.x;
  const int t = threadIdx.x;  // 128
  const float4 v = *(const float4*)(x + (size_t)row * FEAT + t * 4);
  double s = (double)v.x * v.x + (double)v.y * v.y + (double)v.z * v.z + (double)v.w * v.w;
  __shared__ double red[128];
  red[t] = s;
  __syncthreads();
  for (int o = 64; o > 0; o >>= 1) {
    if (t < o) red[t] += red[t + o];
    __syncthreads();
  }
  const double inv = 1.0 / fmax(sqrt(red[0]), 1e-12);
  const float finv = (float)inv;
  unsigned short hf[4] = {f2h(v.x), f2h(v.y), f2h(v.z), f2h(v.w)};
  *(uint2*)(xf + (size_t)row * FEAT + t * 4) = *(uint2*)hf;
  unsigned char e8[4] = {f2e8(v.x * finv), f2e8(v.y * finv), f2e8(v.z * finv),
                         f2e8(v.w * finv)};
  const int kb = t >> 4;
  const int ko = (t * 4) & 63;
  *(unsigned int*)(xn8 + ((size_t)kb * N_NODES + row) * 64 + ko) = *(unsigned int*)e8;
  if (t == 0) rinv[row] = inv;
}

// -------------------- all 4 weight transposes + f16 in one launch --------------------
__global__ void k_wtall(const float* __restrict__ W_s1, const float* __restrict__ W_t1,
                        const float* __restrict__ W_s2, const float* __restrict__ W_t2,
                        unsigned short* __restrict__ Wt_s1, unsigned short* __restrict__ Wt_t1,
                        unsigned short* __restrict__ Wt_s2, unsigned short* __restrict__ Wt_t2) {
  int idx = blockIdx.x * 256 + threadIdx.x;
  const int n1 = FEAT * HID;
  const int n2 = HID * EMB;
  if (idx < n1) {
    const int n = idx / FEAT, k = idx % FEAT;
    Wt_s1[idx] = f2h(W_s1[(size_t)k * HID + n]);
    return;
  }
  idx -= n1;
  if (idx < n1) {
    const int n = idx / FEAT, k = idx % FEAT;
    Wt_t1[idx] = f2h(W_t1[(size_t)k * HID + n]);
    return;
  }
  idx -= n1;
  if (idx < n2) {
    const int n = idx / HID, k = idx % HID;
    Wt_s2[idx] = f2h(W_s2[(size_t)k * EMB + n]);
    return;
  }
  idx -= n2;
  if (idx < n2) {
    const int n = idx / HID, k = idx % HID;
    Wt_t2[idx] = f2h(W_t2[(size_t)k * EMB + n]);
  }
}

// ---- sim GEMM (upper triangle, 256x256 tile, fp8 K-blocked, BK=64) + two-phase epilogue ----
// 512 thr / 8 waves (2 row-halves x 4 col-quarters), per-wave 128x64 (8x4 frags).
// 3-stage LDS ring (96KB), depth-2 prefetch, counted vmcnt(8). Halves staged bytes vs 128^2.
__global__ __launch_bounds__(512) void k_simgemm(const unsigned char* __restrict__ xn8,
                                                 unsigned int* __restrict__ cap_buf,
                                                 int* __restrict__ cnt_row) {
  __shared__ __align__(16) unsigned char As[3][16384];
  __shared__ __align__(16) unsigned char Bs[3][16384];

  const int t = threadIdx.x;
  const int lane = t & 63;
  const int w = t >> 6;
  const int lr = lane & 15;
  const int lk = lane >> 4;
  const int wr = (w >> 2) * 128;  // 0 or 128
  const int wc = (w & 3) * 64;    // 0,64,128,192

  // bijective XCD remap: 820 = 8*102 + 4
  const int xcd = blockIdx.x & 7;
  const int idx = blockIdx.x >> 3;
  const int wg = (xcd < 4) ? xcd * 103 + idx : 4 * 103 + (xcd - 4) * 102 + idx;
  int bi = 0;
  while ((bi + 1) * NTB2 - (bi + 1) * bi / 2 <= wg) ++bi;
  const int bj = bi + (wg - (bi * NTB2 - bi * (bi - 1) / 2));
  const int arow0 = bi * 256;
  const int bcol0 = bj * 256;

  // K-blocked: tile rows contiguous (64B stride). 1024 slots of 16B each matrix; 512 thr x 2.
  auto stage = [&](int s, int k0) {
    const unsigned char* kbp = xn8 + (size_t)(k0 >> 6) * N_NODES * 64;
#pragma unroll
    for (int it = 0; it < 2; ++it) {
      const int slot = it * 512 + t;
      const int r = slot >> 2;
      const int qs = (slot & 3) ^ ((r >> 1) & 3);  // source pre-swizzle
      {
        const int gr = min(arow0 + r, N_NODES - 1);
        gload_lds16(kbp + (size_t)gr * 64 + qs * 16, &As[s][(it * 512 + w * 64) * 16]);
      }
      {
        const int gc = min(bcol0 + r, N_NODES - 1);
        gload_lds16(kbp + (size_t)gc * 64 + qs * 16, &Bs[s][(it * 512 + w * 64) * 16]);
      }
    }
  };

  f32x4 acc[8][4];
#pragma unroll
  for (int m = 0; m < 8; ++m)
#pragma unroll
    for (int n = 0; n < 4; ++n) acc[m][n] = (f32x4){0.f, 0.f, 0.f, 0.f};

  stage(0, 0);
  stage(1, 64);

  const int NT = FEAT / 64;  // 8
  int cur = 0, nxt = 2;
  for (int kt = 0; kt < NT; ++kt) {
    if (kt + 2 < NT) {
      stage(nxt, (kt + 2) * 64);
      asm volatile("s_waitcnt vmcnt(8)" ::: "memory");
    } else if (kt + 1 < NT) {
      asm volatile("s_waitcnt vmcnt(4)" ::: "memory");
    } else {
      asm volatile("s_waitcnt vmcnt(0)" ::: "memory");
    }
    __builtin_amdgcn_sched_barrier(0);
    __builtin_amdgcn_s_barrier();
    const unsigned char* Ab = As[cur];
    const unsigned char* Bb = Bs[cur];
#pragma unroll
    for (int h = 0; h < 2; ++h) {
      long av[8], bv[4];
#pragma unroll
      for (int m = 0; m < 8; ++m) {
        const int row = wr + m * 16 + lr;
        const int sl = (h * 2 + (lk >> 1)) ^ ((row >> 1) & 3);
        av[m] = *(const long*)(Ab + row * 64 + sl * 16 + (lk & 1) * 8);
      }
#pragma unroll
      for (int n = 0; n < 4; ++n) {
        const int row = wc + n * 16 + lr;
        const int sl = (h * 2 + (lk >> 1)) ^ ((row >> 1) & 3);
        bv[n] = *(const long*)(Bb + row * 64 + sl * 16 + (lk & 1) * 8);
      }
      __builtin_amdgcn_s_setprio(1);
#pragma unroll
      for (int m = 0; m < 8; ++m)
#pragma unroll
        for (int n = 0; n < 4; ++n)
          acc[m][n] = __builtin_amdgcn_mfma_f32_16x16x32_fp8_fp8(av[m], bv[n], acc[m][n], 0, 0, 0);
      __builtin_amdgcn_s_setprio(0);
    }
    asm volatile("" ::: "memory");
    if (kt + 1 < NT) __builtin_amdgcn_s_barrier();
    cur = (cur == 2) ? 0 : cur + 1;
    nxt = (nxt == 2) ? 0 : nxt + 1;
  }

  // ---- two-phase epilogue: LDS hit queue (As ring, 48KB), then parallel drain ----
  // C/D layout: col = lane&15, row = (lane>>4)*4 + reg
  __syncthreads();
  unsigned* hq = (unsigned*)&As[0][0];  // 12288 u32 capacity, QCAP2=8192 used
  int* hnp = (int*)&Bs[0][0];           // Bs dead after compute
  if (t == 0) *hnp = 0;
  __syncthreads();
  const bool offdiag = (bi != bj);
#pragma unroll
  for (int m = 0; m < 8; ++m) {
    const int lrow0 = wr + m * 16 + lk * 4;
#pragma unroll
    for (int n = 0; n < 4; ++n) {
      const int lcol = wc + n * 16 + lr;
#pragma unroll
      for (int q = 0; q < 4; ++q) {
        const float v = acc[m][n][q];
        if (v > TAU && (arow0 + lrow0 + q) < N_NODES && (bcol0 + lcol) < N_NODES) {
          const int p = atomicAdd(hnp, 1);
          if (p < QCAP2)
            hq[p] = ((unsigned)f2h(v) << 16) | ((unsigned)(lrow0 + q) << 8) | (unsigned)lcol;
        }
      }
    }
  }
  __syncthreads();
  const int H = *hnp;
  if (H <= QCAP2) {
    for (int e = t; e < H; e += 512) {
      const unsigned pk = hq[e];
      const int gr = arow0 + (int)((pk >> 8) & 255u);
      const int gc = bcol0 + (int)(pk & 255u);
      const unsigned hv = pk >> 16;
      {
        const int pos = atomicAdd(&cnt_row[gr], 1);
        if (pos < CAP) cap_buf[(size_t)gr * CAP + pos] = (hv << 16) | (unsigned)gc;
      }
      if (offdiag) {
        const int pos = atomicAdd(&cnt_row[gc], 1);
        if (pos < CAP) cap_buf[(size_t)gc * CAP + pos] = (hv << 16) | (unsigned)gr;
      }
    }
  } else {
    // overflow (never expected): direct per-element walk
#pragma unroll
    for (int m = 0; m < 8; ++m) {
      const int rb = arow0 + wr + m * 16 + lk * 4;
#pragma unroll
      for (int n = 0; n < 4; ++n) {
        const int gc = bcol0 + wc + n * 16 + lr;
        if (gc < N_NODES) {
#pragma unroll
          for (int q = 0; q < 4; ++q) {
            const float v = acc[m][n][q];
            const int gr = rb + q;
            if (v > TAU && gr < N_NODES) {
              const unsigned short hv = f2h(v);
              {
                const int pos = atomicAdd(&cnt_row[gr], 1);
                if (pos < CAP)
                  cap_buf[(size_t)gr * CAP + pos] = ((unsigned)hv << 16) | (unsigned)gc;
              }
              if (offdiag) {
                const int pos = atomicAdd(&cnt_row[gc], 1);
                if (pos < CAP)
                  cap_buf[(size_t)gc * CAP + pos] = ((unsigned)hv << 16) | (unsigned)gr;
              }
            }
          }
        }
      }
    }
  }
}

// ---- fused select + exact f64 rescore -> 9 neighbors + topology degree count ----
__global__ __launch_bounds__(256) void k_knn(const float* __restrict__ x,
                                             const double* __restrict__ rinv,
                                             const unsigned int* __restrict__ cap_buf,
                                             const int* __restrict__ cnt_row,
                                             int* __restrict__ nb, int* __restrict__ flags,
                                             int* __restrict__ cnt_t) {
  const int i = blockIdx.x;
  const int t = threadIdx.x;
  const int lane = t & 63;
  const int wave = t >> 6;
  __shared__ unsigned pp[CAP];
  __shared__ int sel[NSEL];
  __shared__ float xi[FEAT];
  __shared__ double dsv[NSEL];
  __shared__ int safe_cnt;

  const int cnt = cnt_row[i];
  if (cnt > CAP || cnt < NSEL) {
    if (t == 0) flags[i] = 1;
    return;
  }
  if (t == 0) { flags[i] = 0; safe_cnt = 0; }
  const int L = cnt;
  if (t < L) pp[t] = cap_buf[(size_t)i * CAP + t];
  xi[t] = x[(size_t)i * FEAT + t];
  xi[t + 256] = x[(size_t)i * FEAT + t + 256];
  __syncthreads();

  if (t < L) {
    const unsigned p = pp[t];
    if (h2f((unsigned short)(p >> 16)) >= SAFE_VAL) atomicAdd(&safe_cnt, 1);
    int rk = 0;
    for (int j = 0; j < L; ++j) rk += (pp[j] > p);
    if (rk < NSEL) sel[rk] = (int)(p & 0xffffu);
  }
  __syncthreads();
  if (safe_cnt < KTOP) {
    if (t == 0) flags[i] = 1;
    return;
  }

  const double ri = rinv[i];
  const float4 v0 = *(const float4*)(xi + lane * 8);
  const float4 v1 = *(const float4*)(xi + lane * 8 + 4);
  // 2 candidates in flight per iteration (MLP)
#pragma unroll
  for (int qq = 0; qq < 6; qq += 2) {
    const int c0i = wave * 6 + qq, c1i = c0i + 1;
    const int ci0 = sel[c0i], ci1 = sel[c1i];
    const float4* xr0 = (const float4*)(x + (size_t)ci0 * FEAT);
    const float4* xr1 = (const float4*)(x + (size_t)ci1 * FEAT);
    const float4 a0 = xr0[lane * 2];
    const float4 a1 = xr0[lane * 2 + 1];
    const float4 b0 = xr1[lane * 2];
    const float4 b1 = xr1[lane * 2 + 1];
    double s0 = (double)a0.x * (double)v0.x + (double)a0.y * (double)v0.y +
                (double)a0.z * (double)v0.z + (double)a0.w * (double)v0.w +
                (double)a1.x * (double)v1.x + (double)a1.y * (double)v1.y +
                (double)a1.z * (double)v1.z + (double)a1.w * (double)v1.w;
    double s1 = (double)b0.x * (double)v0.x + (double)b0.y * (double)v0.y +
                (double)b0.z * (double)v0.z + (double)b0.w * (double)v0.w +
                (double)b1.x * (double)v1.x + (double)b1.y * (double)v1.y +
                (double)b1.z * (double)v1.z + (double)b1.w * (double)v1.w;
#pragma unroll
    for (int off = 1; off < 64; off <<= 1) {
      s0 += __shfl_xor(s0, off);
      s1 += __shfl_xor(s1, off);
    }
    if (lane == 0) {
      dsv[c0i] = s0 * ri * rinv[ci0];
      dsv[c1i] = s1 * ri * rinv[ci1];
    }
  }
  __syncthreads();

  if (t < NSEL) {
    const double v = dsv[t];
    const int id = sel[t];
    int rk = 0;
    for (int j = 0; j < NSEL; ++j)
      rk += (dsv[j] > v) || (dsv[j] == v && sel[j] < id);
    if (rk >= 1 && rk < KTOP) {
      nb[(size_t)i * NNB + (rk - 1)] = id;
      atomicAdd(&cnt_t[id], 1);
    }
  }
}

// ---- fallback: exact full scan for flagged rows (expected: none) ----
__global__ __launch_bounds__(256) void k_fallback(const float* __restrict__ x,
                                                  const double* __restrict__ rinv,
                                                  const int* __restrict__ flags,
                                                  int* __restrict__ nb,
                                                  int* __restrict__ cnt_t) {
  const int i = blockIdx.x;
  if (!flags[i]) return;
  const int t = threadIdx.x;
  __shared__ float xi[FEAT];
  __shared__ double cval[256];
  __shared__ double bestv[NNB];
  __shared__ int besti[NNB];
  for (int k = t; k < FEAT; k += 256) xi[k] = x[(size_t)i * FEAT + k];
  if (t < NNB) { bestv[t] = -1e300; besti[t] = 0x7fffffff; }
  __syncthreads();
  const double ri = rinv[i];
  for (int c0 = 0; c0 < N_NODES; c0 += 256) {
    const int c = c0 + t;
    double s = -1e300;
    if (c < N_NODES && c != i) {
      s = 0.0;
      for (int k = 0; k < FEAT; ++k) s += (double)xi[k] * (double)x[(size_t)c * FEAT + k];
      s *= ri * rinv[c];
    }
    cval[t] = s;
    __syncthreads();
    if (t == 0) {
      for (int j = 0; j < 256; ++j) {
        const int c2 = c0 + j;
        const double v = cval[j];
        if (v == -1e300) continue;
        int pos = NNB;
        for (int q = 0; q < NNB; ++q) {
          if (v > bestv[q] || (v == bestv[q] && c2 < besti[q])) { pos = q; break; }
        }
        if (pos < NNB) {
          for (int q = NNB - 1; q > pos; --q) { bestv[q] = bestv[q - 1]; besti[q] = besti[q - 1]; }
          bestv[pos] = v; besti[pos] = c2;
        }
      }
    }
    __syncthreads();
  }
  if (t < NNB) {
    nb[(size_t)i * NNB + t] = besti[t];
    atomicAdd(&cnt_t[besti[t]], 1);
  }
}

// -------------------- CSR build helpers --------------------
__global__ void k_zero3(int* __restrict__ a, int* __restrict__ b, int* __restrict__ c) {
  const int i = blockIdx.x * blockDim.x + threadIdx.x;
  if (i < N_NODES) { a[i] = 0; b[i] = 0; c[i] = 0; }
}

__global__ void k_count(const int* __restrict__ dsts, int ne, int* __restrict__ cnt) {
  const int e = blockIdx.x * blockDim.x + threadIdx.x;
  if (e < ne) atomicAdd(&cnt[dsts[e]], 1);
}

// both scans concurrently, wave-shfl based
__global__ void k_scan2(const int* __restrict__ cnt0, int* __restrict__ off0,
                        int* __restrict__ cur0, float* __restrict__ dinv0,
                        const int* __restrict__ cnt1, int* __restrict__ off1,
                        int* __restrict__ cur1, float* __restrict__ dinv1) {
  const int* cnt = blockIdx.x ? cnt1 : cnt0;
  int* off = blockIdx.x ? off1 : off0;
  int* cur = blockIdx.x ? cur1 : cur0;
  float* dinv = blockIdx.x ? dinv1 : dinv0;
  __shared__ int wsum[16];
  __shared__ int woff[16];
  __shared__ int base_s, tot_s;
  const int t = threadIdx.x;  // 1024
  const int lane = t & 63, wid = t >> 6;
  if (t == 0) base_s = 0;
  __syncthreads();
  for (int b0 = 0; b0 < N_NODES; b0 += 1024) {
    const int i = b0 + t;
    const int v = (i < N_NODES) ? cnt[i] : 0;
    int inc = v;
#pragma unroll
    for (int o = 1; o < 64; o <<= 1) {
      const int u = __shfl_up(inc, o, 64);
      if (lane >= o) inc += u;
    }
    if (lane == 63) wsum[wid] = inc;
    __syncthreads();
    if (wid == 0) {
      const int ws = (lane < 16) ? wsum[lane] : 0;
      int wi = ws;
#pragma unroll
      for (int o = 1; o < 16; o <<= 1) {
        const int u = __shfl_up(wi, o, 64);
        if (lane >= o) wi += u;
      }
      if (lane < 16) woff[lane] = wi - ws;
      if (lane == 15) tot_s = wi;
    }
    __syncthreads();
    if (i < N_NODES) {
      const int excl = base_s + woff[wid] + (inc - v);
      off[i] = excl;
      cur[i] = excl;
      dinv[i] = rsqrtf((float)(v + 1));
    }
    __syncthreads();
    if (t == 0) base_s += tot_s;
    __syncthreads();
  }
  if (t == 0) off[N_NODES] = base_s;
}

__global__ void k_scatter_s(const int* __restrict__ src, const int* __restrict__ dst, int ne,
                            int* __restrict__ cur, int* __restrict__ csr) {
  const int e = blockIdx.x * blockDim.x + threadIdx.x;
  if (e < ne) {
    const int p = atomicAdd(&cur[dst[e]], 1);
    csr[p] = src[e];
  }
}

__global__ void k_scatter_t(const int* __restrict__ nb, int* __restrict__ cur,
                            int* __restrict__ csr) {
  const int e = blockIdx.x * blockDim.x + threadIdx.x;
  if (e < N_NODES * NNB) {
    const int i = e / NNB;
    const int v = nb[e];
    const int p = atomicAdd(&cur[v], 1);
    csr[p] = i;
  }
}

// ---- f16 MFMA feature GEMM (merged pair), 3-stage ring, f16 out ----
__global__ __launch_bounds__(256) void k_fgemm2(const unsigned short* __restrict__ A0,
                                                const unsigned short* __restrict__ A1,
                                                const unsigned short* __restrict__ Bt0,
                                                const unsigned short* __restrict__ Bt1,
                                                unsigned short* __restrict__ C0,
                                                unsigned short* __restrict__ C1,
                                                int M, int K, int N) {
  __shared__ __align__(16) unsigned short As[3][4096];
  __shared__ __align__(16) unsigned short Bs[3][4096];
  const int t = threadIdx.x;
  const int lane = t & 63, w = t >> 6;
  const int lr = lane & 15, lk = lane >> 4;
  const int wr = (w >> 1) * 64, wc = (w & 1) * 64;
  const int nbn = N >> 7;
  const int half = blockIdx.y / nbn;
  const unsigned short* A = half ? A1 : A0;
  const unsigned short* Bt = half ? Bt1 : Bt0;
  unsigned short* C = half ? C1 : C0;
  const int arow0 = blockIdx.x * 128, bcol0 = (blockIdx.y % nbn) * 128;

  auto stage = [&](int s, int k0) {
#pragma unroll
    for (int it = 0; it < 2; ++it) {
      const int slot = it * 256 + w * 64 + lane;
      const int r = slot >> 2;
      const int qs = (slot & 3) ^ ((r >> 1) & 3);
      {
        const int gr = min(arow0 + r, M - 1);
        gload_lds16(A + (size_t)gr * K + k0 + qs * 8, &As[s][(it * 256 + w * 64) * 8]);
      }
      {
        const int gc = min(bcol0 + r, N - 1);
        gload_lds16(Bt + (size_t)gc * K + k0 + qs * 8, &Bs[s][(it * 256 + w * 64) * 8]);
      }
    }
  };

  f32x4 acc[4][4];
#pragma unroll
  for (int m = 0; m < 4; ++m)
#pragma unroll
    for (int n = 0; n < 4; ++n) acc[m][n] = (f32x4){0.f, 0.f, 0.f, 0.f};

  stage(0, 0);
  if (K > 32) stage(1, 32);

  const int NT = K >> 5;
  int cur = 0, nxt = 2;
  for (int kt = 0; kt < NT; ++kt) {
    if (kt + 2 < NT) {
      stage(nxt, (kt + 2) << 5);
      asm volatile("s_waitcnt vmcnt(8)" ::: "memory");
    } else if (kt + 1 < NT) {
      asm volatile("s_waitcnt vmcnt(4)" ::: "memory");
    } else {
      asm volatile("s_waitcnt vmcnt(0)" ::: "memory");
    }
    __builtin_amdgcn_sched_barrier(0);
    __builtin_amdgcn_s_barrier();
    const unsigned short* Ab = As[cur];
    const unsigned short* Bb = Bs[cur];
    short8 a[4], b[4];
#pragma unroll
    for (int m = 0; m < 4; ++m) {
      const int row = wr + m * 16 + lr;
      a[m] = *(const short8*)(Ab + (((row << 2) | (lk ^ ((row >> 1) & 3))) << 3));
    }
#pragma unroll
    for (int n = 0; n < 4; ++n) {
      const int row = wc + n * 16 + lr;
      b[n] = *(const short8*)(Bb + (((row << 2) | (lk ^ ((row >> 1) & 3))) << 3));
    }
    __builtin_amdgcn_s_setprio(1);
#pragma unroll
    for (int m = 0; m < 4; ++m)
#pragma unroll
      for (int n = 0; n < 4; ++n)
        acc[m][n] = __builtin_amdgcn_mfma_f32_16x16x32_f16(a[m], b[n], acc[m][n], 0, 0, 0);
    __builtin_amdgcn_s_setprio(0);
    asm volatile("" ::: "memory");
    if (kt + 1 < NT) __builtin_amdgcn_s_barrier();
    cur = (cur == 2) ? 0 : cur + 1;
    nxt = (nxt == 2) ? 0 : nxt + 1;
  }

#pragma unroll
  for (int m = 0; m < 4; ++m) {
    const int rb = arow0 + wr + m * 16 + lk * 4;
#pragma unroll
    for (int n = 0; n < 4; ++n) {
      const int gc = bcol0 + wc + n * 16 + lr;
#pragma unroll
      for (int q = 0; q < 4; ++q) {
        const int gm = rb + q;
        if (gm < M) C[(size_t)gm * N + gc] = f2h(acc[m][n][q]);
      }
    }
  }
}

// ---- layer-1 aggregation, both branches in one launch (blockIdx.y) ----
__global__ void k_agg_h2(const unsigned short* __restrict__ h0,
                         const unsigned short* __restrict__ h1,
                         const float* __restrict__ bias0, const float* __restrict__ bias1,
                         const float* __restrict__ dinv0, const float* __restrict__ dinv1,
                         const int* __restrict__ off0, const int* __restrict__ off1,
                         const int* __restrict__ csr0, const int* __restrict__ csr1,
                         unsigned short* __restrict__ out0, unsigned short* __restrict__ out1) {
  const int br = blockIdx.y;
  const unsigned short* h = br ? h1 : h0;
  const float* bias = br ? bias1 : bias0;
  const float* dinv = br ? dinv1 : dinv0;
  const int* off = br ? off1 : off0;
  const int* csr = br ? csr1 : csr0;
  unsigned short* out = br ? out1 : out0;
  const int v = blockIdx.x;
  const int c = threadIdx.x;  // HID
  const float dv = dinv[v];
  float acc = h2f(h[(size_t)v * HID + c]) * dv;
  const int s0 = off[v], s1 = off[v + 1];
  int e = s0;
  for (; e + 1 < s1; e += 2) {
    const int sa = csr[e], sb = csr[e + 1];
    const float ha = h2f(h[(size_t)sa * HID + c]), hb = h2f(h[(size_t)sb * HID + c]);
    acc += ha * dinv[sa] + hb * dinv[sb];
  }
  if (e < s1) {
    const int sa = csr[e];
    acc += h2f(h[(size_t)sa * HID + c]) * dinv[sa];
  }
  acc = acc * dv + bias[c];
  out[(size_t)v * HID + c] = f2h(fmaxf(acc, 0.f));
}

// ---- layer-2 aggregation (both branches) + fusion + Student-t, fused ----
__global__ void k_aggfuse(const unsigned short* __restrict__ h2_s,
                          const unsigned short* __restrict__ h2_t,
                          const float* __restrict__ b_s2, const float* __restrict__ b_t2,
                          const float* __restrict__ dinv_s, const int* __restrict__ off_s,
                          const int* __restrict__ csr_s, const float* __restrict__ dinv_t,
                          const int* __restrict__ off_t, const int* __restrict__ csr_t,
                          const float* __restrict__ fw, const float* __restrict__ cent,
                          float* __restrict__ out_z, float* __restrict__ out_q) {
  const int v = blockIdx.x;
  const int c = threadIdx.x;  // 128
  __shared__ float zsh[EMB];
  __shared__ float cs[NC][EMB];
  __shared__ float qv[NC];
  __shared__ float qs;
  for (int k = c; k < NC * EMB; k += 128) ((float*)cs)[k] = cent[k];
  float zs, zt;
  {
    const float dv = dinv_s[v];
    float acc = h2f(h2_s[(size_t)v * EMB + c]) * dv;
    const int s0 = off_s[v], s1 = off_s[v + 1];
    int e = s0;
    for (; e + 1 < s1; e += 2) {
      const int sa = csr_s[e], sb = csr_s[e + 1];
      acc += h2f(h2_s[(size_t)sa * EMB + c]) * dinv_s[sa] +
             h2f(h2_s[(size_t)sb * EMB + c]) * dinv_s[sb];
    }
    if (e < s1) {
      const int sa = csr_s[e];
      acc += h2f(h2_s[(size_t)sa * EMB + c]) * dinv_s[sa];
    }
    zs = acc * dv + b_s2[c];
  }
  {
    const float dv = dinv_t[v];
    float acc = h2f(h2_t[(size_t)v * EMB + c]) * dv;
    const int s0 = off_t[v], s1 = off_t[v + 1];
    int e = s0;
    for (; e + 1 < s1; e += 2) {
      const int sa = csr_t[e], sb = csr_t[e + 1];
      acc += h2f(h2_t[(size_t)sa * EMB + c]) * dinv_t[sa] +
             h2f(h2_t[(size_t)sb * EMB + c]) * dinv_t[sb];
    }
    if (e < s1) {
      const int sa = csr_t[e];
      acc += h2f(h2_t[(size_t)sa * EMB + c]) * dinv_t[sa];
    }
    zt = acc * dv + b_t2[c];
  }
  const float beta = 1.f / (1.f + expf(-fw[0]));
  const float z = beta * zs + (1.f - beta) * zt;
  out_z[(size_t)v * EMB + c] = z;
  zsh[c] = z;
  __syncthreads();
  if (c < NC) {
    float s = 0.f;
    for (int k = 0; k < EMB; ++k) {
      const float d = zsh[k] - cs[c][k];
      s += d * d;
    }
    qv[c] = 1.f / (1.f + s);
  }
  __syncthreads();
  if (c == 0) {
    float s = 0.f;
    for (int k = 0; k < NC; ++k) s += qv[k];
    qs = s;
  }
  __syncthreads();
  if (c < NC) out_q[(size_t)v * NC + c] = qv[c] / qs;
}

extern "C" void kernel_launch(void* const* d_in, const int* in_sizes, int n_in, void* d_out,
                              int out_size, void* d_ws, size_t ws_size, hipStream_t stream) {
  const float* x = (const float*)d_in[0];
  const int* ei = (const int*)d_in[1];
  const float* W_s1 = (const float*)d_in[2];
  const float* b_s1 = (const float*)d_in[3];
  const float* W_s2 = (const float*)d_in[4];
  const float* b_s2 = (const float*)d_in[5];
  const float* W_t1 = (const float*)d_in[6];
  const float* b_t1 = (const float*)d_in[7];
  const float* W_t2 = (const float*)d_in[8];
  const float* b_t2 = (const float*)d_in[9];
  const float* fw = (const float*)d_in[10];
  const float* cent = (const float*)d_in[11];
  float* out_z = (float*)d_out;
  float* out_q = out_z + (size_t)N_NODES * EMB;

  char* w = (char*)d_ws;
  size_t o = 0;
  auto alloc = [&](size_t bytes) -> void* {
    void* p = w + o;
    o += (bytes + 255) & ~(size_t)255;
    return p;
  };
  // xn8 (K-blocked fp8, 5.12MB; region 10.24MB) -> h1_s f16 after simgemm
  unsigned char* xn8 = (unsigned char*)alloc((size_t)N_NODES * FEAT * 2);
  unsigned short* h1_s = (unsigned short*)xn8;
  // xf (raw f16) -> h2_s/h2_t f16 after layer-1 GEMMs
  unsigned short* xf = (unsigned short*)alloc((size_t)N_NODES * FEAT * 2);
  unsigned short* h2_s = xf;
  unsigned short* h2_t = xf + (size_t)N_NODES * EMB;
  double* rinv = (double*)alloc((size_t)N_NODES * 8);
  // cap_buf (5.12 MB) -> r1_s f16 after k_knn
  unsigned int* cap_buf = (unsigned int*)alloc((size_t)N_NODES * CAP * 4);
  unsigned short* r1_s = (unsigned short*)cap_buf;
  unsigned short* r1_t = (unsigned short*)alloc((size_t)N_NODES * HID * 2);
  unsigned short* h1_t = (unsigned short*)alloc((size_t)N_NODES * HID * 2);
  int* nb = (int*)alloc((size_t)N_NODES * NNB * 4);
  int* cnt_s = (int*)alloc((size_t)N_NODES * 4);
  int* off_s = (int*)alloc((size_t)(N_NODES + 1) * 4);
  int* cur_s = (int*)alloc((size_t)N_NODES * 4);
  float* dinv_s = (float*)alloc((size_t)N_NODES * 4);
  int* cnt_t = (int*)alloc((size_t)N_NODES * 4);
  int* off_t = (int*)alloc((size_t)(N_NODES + 1) * 4);
  int* cur_t = (int*)alloc((size_t)N_NODES * 4);
  float* dinv_t = (float*)alloc((size_t)N_NODES * 4);
  int* csr_s = (int*)alloc((size_t)NE_EDGES * 4);
  int* csr_t = (int*)alloc((size_t)N_NODES * NNB * 4);
  int* cnt_row = (int*)alloc((size_t)N_NODES * 4);
  int* flags = (int*)alloc((size_t)N_NODES * 4);
  unsigned short* Wt_s1 = (unsigned short*)alloc((size_t)FEAT * HID * 2);
  unsigned short* Wt_t1 = (unsigned short*)alloc((size_t)FEAT * HID * 2);
  unsigned short* Wt_s2 = (unsigned short*)alloc((size_t)HID * EMB * 2);
  unsigned short* Wt_t2 = (unsigned short*)alloc((size_t)HID * EMB * 2);

  const int* e_src = ei;
  const int* e_dst = ei + NE_EDGES;

  // 1. norms (K-blocked fp8 + f16 raw) + all weight transposes
  k_norms<<<N_NODES, 128, 0, stream>>>(x, xn8, xf, rinv);
  {
    const int tot = 2 * FEAT * HID + 2 * HID * EMB;
    k_wtall<<<(tot + 255) / 256, 256, 0, stream>>>(W_s1, W_t1, W_s2, W_t2, Wt_s1, Wt_t1, Wt_s2,
                                                   Wt_t2);
  }
  // 2. zero counters + structural degrees
  k_zero3<<<(N_NODES + 255) / 256, 256, 0, stream>>>(cnt_s, cnt_t, cnt_row);
  k_count<<<(NE_EDGES + 255) / 256, 256, 0, stream>>>(e_dst, NE_EDGES, cnt_s);
  // 3. sim GEMM (256^2 upper triangle, fp8 K-blocked) + filter
  k_simgemm<<<NPAIR2, 512, 0, stream>>>(xn8, cap_buf, cnt_row);
  // 4. select + f64 rescore (+ topology degree counting); fallback net
  k_knn<<<N_NODES, 256, 0, stream>>>(x, rinv, cap_buf, cnt_row, nb, flags, cnt_t);
  k_fallback<<<N_NODES, 256, 0, stream>>>(x, rinv, flags, nb, cnt_t);
  // 5. both scans + scatters
  k_scan2<<<2, 1024, 0, stream>>>(cnt_s, off_s, cur_s, dinv_s, cnt_t, off_t, cur_t, dinv_t);
  k_scatter_s<<<(NE_EDGES + 255) / 256, 256, 0, stream>>>(e_src, e_dst, NE_EDGES, cur_s, csr_s);
  k_scatter_t<<<(N_NODES * NNB + 255) / 256, 256, 0, stream>>>(nb, cur_t, csr_t);
  // 6. layer-1 GEMMs (h1_s aliases xn8: safe, simgemm done)
  {
    dim3 g1(NTB, 2 * (HID / 128));
    k_fgemm2<<<g1, 256, 0, stream>>>(xf, xf, Wt_s1, Wt_t1, h1_s, h1_t, N_NODES, FEAT, HID);
  }
  // 7. layer-1 aggregation, both branches (r1_s overwrites cap_buf: safe, k_knn done)
  {
    dim3 ga(N_NODES, 2);
    k_agg_h2<<<ga, HID, 0, stream>>>(h1_s, h1_t, b_s1, b_t1, dinv_s, dinv_t, off_s, off_t, csr_s,
                                     csr_t, r1_s, r1_t);
  }
  // 8. layer-2 GEMMs (h2_s/h2_t alias xf: safe, layer-1 done)
  {
    dim3 g2(NTB, 2 * (EMB / 128));
    k_fgemm2<<<g2, 256, 0, stream>>>(r1_s, r1_t, Wt_s2, Wt_t2, h2_s, h2_t, N_NODES, HID, EMB);
  }
  // 9. layer-2 aggregation + fusion + soft assignment (fused)
  k_aggfuse<<<N_NODES, EMB, 0, stream>>>(h2_s, h2_t, b_s2, b_t2, dinv_s, off_s, csr_s, dinv_t,
                                         off_t, csr_t, fw, cent, out_z, out_q);
}

// Round 14
// 317.934 us; speedup vs baseline: 1.0541x; 1.0541x over previous
//
#include <hip/hip_runtime.h>
#include <math.h>

#define N_NODES 10000
#define FEAT 512
#define HID 256
#define EMB 128
#define NC 10
#define NE_EDGES 160000
#define KTOP 10
#define NNB 9

#define CAP 128          // per-row candidate buffer capacity
#define NSEL 24          // candidates f64-rescored (fp8 phase-1 -> wider margin)
#define TAU 0.11f        // store threshold (sims ~ N(0,0.0442), s10 ~ 0.19)
#define SAFE_VAL 0.12f   // need >=10 stored above this, else fallback
#define NTB 79           // 79 tiles of 128
#define NPAIR 3160       // 79*80/2 upper-triangle blocks
#define QCAP 2048        // per-block LDS hit queue (expected ~105 hits)

typedef __attribute__((ext_vector_type(8))) short short8;
typedef __attribute__((ext_vector_type(4))) float f32x4;

typedef const __attribute__((address_space(1))) unsigned int* gas1_t;
typedef __attribute__((address_space(3))) unsigned int* las3_t;

__device__ __forceinline__ void gload_lds16(const void* g, void* l) {
  __builtin_amdgcn_global_load_lds((gas1_t)g, (las3_t)l, 16, 0, 0);
}

__device__ __forceinline__ unsigned short f2h(float f) {
  _Float16 h = (_Float16)f;
  return *(unsigned short*)&h;
}
__device__ __forceinline__ float h2f(unsigned short u) {
  _Float16 h = *(_Float16*)&u;
  return (float)h;
}

// f32 -> OCP e4m3fn, RNE (inputs |x| <= 1 here; no inf/nan cases)
__device__ __forceinline__ unsigned char f2e8(float f) {
  const unsigned u = __float_as_uint(f);
  const unsigned sg = (u >> 24) & 0x80u;
  const int e = (int)((u >> 23) & 0xffu) - 127;
  const unsigned m = u & 0x7fffffu;
  if (e >= -6) {
    if (e > 8) return sg | 0x7eu;
    unsigned mant = m >> 20;
    const unsigned rest = m & 0xfffffu;
    if (rest > 0x80000u || (rest == 0x80000u && (mant & 1u))) ++mant;
    unsigned ex = (unsigned)(e + 7);
    if (mant == 8u) { mant = 0u; ++ex; }
    if (ex > 15u || (ex == 15u && mant == 7u)) return sg | 0x7eu;
    return sg | (ex << 3) | mant;
  }
  const float af = fabsf(f);
  const int q = (int)(af * 512.0f + 0.5f);
  if (q > 7) return sg | 0x08u;
  return sg | (unsigned)q;
}

// ---- row norms -> K-blocked fp8 normalized (xn8[kb][node][64]) + f16 raw + f64 inv norms ----
__global__ void k_norms(const float* __restrict__ x, unsigned char* __restrict__ xn8,
                        unsigned short* __restrict__ xf, double* __restrict__ rinv) {
  const int row = blockIdx.x;
  const int t = threadIdx.x;  // 128
  const float4 v = *(const float4*)(x + (size_t)row * FEAT + t * 4);
  double s = (double)v.x * v.x + (double)v.y * v.y + (double)v.z * v.z + (double)v.w * v.w;
  __shared__ double red[128];
  red[t] = s;
  __syncthreads();
  for (int o = 64; o > 0; o >>= 1) {
    if (t < o) red[t] += red[t + o];
    __syncthreads();
  }
  const double inv = 1.0 / fmax(sqrt(red[0]), 1e-12);
  const float finv = (float)inv;
  unsigned short hf[4] = {f2h(v.x), f2h(v.y), f2h(v.z), f2h(v.w)};
  *(uint2*)(xf + (size_t)row * FEAT + t * 4) = *(uint2*)hf;
  unsigned char e8[4] = {f2e8(v.x * finv), f2e8(v.y * finv), f2e8(v.z * finv),
                         f2e8(v.w * finv)};
  const int kb = t >> 4;
  const int ko = (t * 4) & 63;
  *(unsigned int*)(xn8 + ((size_t)kb * N_NODES + row) * 64 + ko) = *(unsigned int*)e8;
  if (t == 0) rinv[row] = inv;
}

// -------------------- all 4 weight transposes + f16 in one launch --------------------
__global__ void k_wtall(const float* __restrict__ W_s1, const float* __restrict__ W_t1,
                        const float* __restrict__ W_s2, const float* __restrict__ W_t2,
                        unsigned short* __restrict__ Wt_s1, unsigned short* __restrict__ Wt_t1,
                        unsigned short* __restrict__ Wt_s2, unsigned short* __restrict__ Wt_t2) {
  int idx = blockIdx.x * 256 + threadIdx.x;
  const int n1 = FEAT * HID;
  const int n2 = HID * EMB;
  if (idx < n1) {
    const int n = idx / FEAT, k = idx % FEAT;
    Wt_s1[idx] = f2h(W_s1[(size_t)k * HID + n]);
    return;
  }
  idx -= n1;
  if (idx < n1) {
    const int n = idx / FEAT, k = idx % FEAT;
    Wt_t1[idx] = f2h(W_t1[(size_t)k * HID + n]);
    return;
  }
  idx -= n1;
  if (idx < n2) {
    const int n = idx / HID, k = idx % HID;
    Wt_s2[idx] = f2h(W_s2[(size_t)k * EMB + n]);
    return;
  }
  idx -= n2;
  if (idx < n2) {
    const int n = idx / HID, k = idx % HID;
    Wt_t2[idx] = f2h(W_t2[(size_t)k * EMB + n]);
  }
}

// ---- sim GEMM (upper triangle, fp8 K-blocked, BK=64), 2-stage ring (32KB -> 4 blocks/CU) ----
__global__ __launch_bounds__(256) void k_simgemm(const unsigned char* __restrict__ xn8,
                                                 unsigned int* __restrict__ cap_buf,
                                                 int* __restrict__ cnt_row) {
  __shared__ __align__(16) unsigned char As[2][8192];
  __shared__ __align__(16) unsigned char Bs[2][8192];
  __shared__ int hn;

  const int t = threadIdx.x;
  const int lane = t & 63;
  const int w = t >> 6;
  const int lr = lane & 15;
  const int lk = lane >> 4;
  const int wr = (w >> 1) * 64, wc = (w & 1) * 64;

  // XCD-chunked bijective remap (3160 = 8*395), then triangular decode (bi <= bj)
  const int bid = (blockIdx.x & 7) * 395 + (blockIdx.x >> 3);
  int bi = (int)((159.0 - sqrt(25281.0 - 8.0 * (double)bid)) * 0.5);
  while ((bi + 1) * NTB - (bi + 1) * bi / 2 <= bid) ++bi;
  while (bi * NTB - bi * (bi - 1) / 2 > bid) --bi;
  const int bj = bi + (bid - (bi * NTB - bi * (bi - 1) / 2));
  const int arow0 = bi * 128;
  const int bcol0 = bj * 128;

  // K-blocked: tile rows contiguous (64B stride)
  auto stage = [&](int s, int k0) {
    const unsigned char* kbp = xn8 + (size_t)(k0 >> 6) * N_NODES * 64;
#pragma unroll
    for (int it = 0; it < 2; ++it) {
      const int slot = it * 256 + t;
      const int r = slot >> 2;
      const int qs = (slot & 3) ^ ((r >> 1) & 3);  // source pre-swizzle
      {
        const int gr = min(arow0 + r, N_NODES - 1);
        gload_lds16(kbp + (size_t)gr * 64 + qs * 16, &As[s][(it * 256 + w * 64) * 16]);
      }
      {
        const int gc = min(bcol0 + r, N_NODES - 1);
        gload_lds16(kbp + (size_t)gc * 64 + qs * 16, &Bs[s][(it * 256 + w * 64) * 16]);
      }
    }
  };

  f32x4 acc[4][4];
#pragma unroll
  for (int m = 0; m < 4; ++m)
#pragma unroll
    for (int n = 0; n < 4; ++n) acc[m][n] = (f32x4){0.f, 0.f, 0.f, 0.f};

  stage(0, 0);

  const int NT = FEAT / 64;  // 8
  for (int kt = 0; kt < NT; ++kt) {
    const int cur = kt & 1;
    if (kt + 1 < NT) {
      stage(cur ^ 1, (kt + 1) * 64);
      asm volatile("s_waitcnt vmcnt(4)" ::: "memory");
    } else {
      asm volatile("s_waitcnt vmcnt(0)" ::: "memory");
    }
    __builtin_amdgcn_sched_barrier(0);
    __builtin_amdgcn_s_barrier();
    const unsigned char* Ab = As[cur];
    const unsigned char* Bb = Bs[cur];
    long av[2][4], bv[2][4];
#pragma unroll
    for (int h = 0; h < 2; ++h) {
#pragma unroll
      for (int m = 0; m < 4; ++m) {
        const int row = wr + m * 16 + lr;
        const int sl = (h * 2 + (lk >> 1)) ^ ((row >> 1) & 3);
        av[h][m] = *(const long*)(Ab + row * 64 + sl * 16 + (lk & 1) * 8);
      }
#pragma unroll
      for (int n = 0; n < 4; ++n) {
        const int row = wc + n * 16 + lr;
        const int sl = (h * 2 + (lk >> 1)) ^ ((row >> 1) & 3);
        bv[h][n] = *(const long*)(Bb + row * 64 + sl * 16 + (lk & 1) * 8);
      }
    }
    __builtin_amdgcn_s_setprio(1);
#pragma unroll
    for (int h = 0; h < 2; ++h)
#pragma unroll
      for (int m = 0; m < 4; ++m)
#pragma unroll
        for (int n = 0; n < 4; ++n)
          acc[m][n] =
              __builtin_amdgcn_mfma_f32_16x16x32_fp8_fp8(av[h][m], bv[h][n], acc[m][n], 0, 0, 0);
    __builtin_amdgcn_s_setprio(0);
    asm volatile("" ::: "memory");
    if (kt + 1 < NT) __builtin_amdgcn_s_barrier();
  }

  // ---- two-phase epilogue: LDS hit queue, then parallel drain ----
  __syncthreads();
  unsigned* hq = (unsigned*)&As[0][0];
  if (t == 0) hn = 0;
  __syncthreads();
  const bool offdiag = (bi != bj);
#pragma unroll
  for (int m = 0; m < 4; ++m) {
    const int lrow0 = wr + m * 16 + lk * 4;
#pragma unroll
    for (int n = 0; n < 4; ++n) {
      const int lcol = wc + n * 16 + lr;
#pragma unroll
      for (int q = 0; q < 4; ++q) {
        const float v = acc[m][n][q];
        if (v > TAU && (arow0 + lrow0 + q) < N_NODES && (bcol0 + lcol) < N_NODES) {
          const int p = atomicAdd(&hn, 1);
          if (p < QCAP)
            hq[p] = ((unsigned)f2h(v) << 16) | ((unsigned)(lrow0 + q) << 7) | (unsigned)lcol;
        }
      }
    }
  }
  __syncthreads();
  const int H = hn;
  if (H <= QCAP) {
    for (int e = t; e < H; e += 256) {
      const unsigned pk = hq[e];
      const int gr = arow0 + (int)((pk >> 7) & 127u);
      const int gc = bcol0 + (int)(pk & 127u);
      const unsigned hv = pk >> 16;
      {
        const int pos = atomicAdd(&cnt_row[gr], 1);
        if (pos < CAP) cap_buf[(size_t)gr * CAP + pos] = (hv << 16) | (unsigned)gc;
      }
      if (offdiag) {
        const int pos = atomicAdd(&cnt_row[gc], 1);
        if (pos < CAP) cap_buf[(size_t)gc * CAP + pos] = (hv << 16) | (unsigned)gr;
      }
    }
  } else {
#pragma unroll
    for (int m = 0; m < 4; ++m) {
      const int rb = arow0 + wr + m * 16 + lk * 4;
#pragma unroll
      for (int n = 0; n < 4; ++n) {
        const int gc = bcol0 + wc + n * 16 + lr;
        if (gc < N_NODES) {
#pragma unroll
          for (int q = 0; q < 4; ++q) {
            const float v = acc[m][n][q];
            const int gr = rb + q;
            if (v > TAU && gr < N_NODES) {
              const unsigned short hv = f2h(v);
              {
                const int pos = atomicAdd(&cnt_row[gr], 1);
                if (pos < CAP)
                  cap_buf[(size_t)gr * CAP + pos] = ((unsigned)hv << 16) | (unsigned)gc;
              }
              if (offdiag) {
                const int pos = atomicAdd(&cnt_row[gc], 1);
                if (pos < CAP)
                  cap_buf[(size_t)gc * CAP + pos] = ((unsigned)hv << 16) | (unsigned)gr;
              }
            }
          }
        }
      }
    }
  }
}

// ---- fused select + exact f64 rescore -> 9 neighbors + topology degree count ----
__global__ __launch_bounds__(256) void k_knn(const float* __restrict__ x,
                                             const double* __restrict__ rinv,
                                             const unsigned int* __restrict__ cap_buf,
                                             const int* __restrict__ cnt_row,
                                             int* __restrict__ nb, int* __restrict__ flags,
                                             int* __restrict__ cnt_t) {
  const int i = blockIdx.x;
  const int t = threadIdx.x;
  const int lane = t & 63;
  const int wave = t >> 6;
  __shared__ unsigned pp[CAP];
  __shared__ int sel[NSEL];
  __shared__ float xi[FEAT];
  __shared__ double dsv[NSEL];
  __shared__ int safe_cnt;

  const int cnt = cnt_row[i];
  if (cnt > CAP || cnt < NSEL) {
    if (t == 0) flags[i] = 1;
    return;
  }
  if (t == 0) { flags[i] = 0; safe_cnt = 0; }
  const int L = cnt;
  if (t < L) pp[t] = cap_buf[(size_t)i * CAP + t];
  xi[t] = x[(size_t)i * FEAT + t];
  xi[t + 256] = x[(size_t)i * FEAT + t + 256];
  __syncthreads();

  if (t < L) {
    const unsigned p = pp[t];
    if (h2f((unsigned short)(p >> 16)) >= SAFE_VAL) atomicAdd(&safe_cnt, 1);
    int rk = 0;
    for (int j = 0; j < L; ++j) rk += (pp[j] > p);
    if (rk < NSEL) sel[rk] = (int)(p & 0xffffu);
  }
  __syncthreads();
  if (safe_cnt < KTOP) {
    if (t == 0) flags[i] = 1;
    return;
  }

  const double ri = rinv[i];
  const float4 v0 = *(const float4*)(xi + lane * 8);
  const float4 v1 = *(const float4*)(xi + lane * 8 + 4);
#pragma unroll
  for (int qq = 0; qq < 6; qq += 2) {
    const int c0i = wave * 6 + qq, c1i = c0i + 1;
    const int ci0 = sel[c0i], ci1 = sel[c1i];
    const float4* xr0 = (const float4*)(x + (size_t)ci0 * FEAT);
    const float4* xr1 = (const float4*)(x + (size_t)ci1 * FEAT);
    const float4 a0 = xr0[lane * 2];
    const float4 a1 = xr0[lane * 2 + 1];
    const float4 b0 = xr1[lane * 2];
    const float4 b1 = xr1[lane * 2 + 1];
    double s0 = (double)a0.x * (double)v0.x + (double)a0.y * (double)v0.y +
                (double)a0.z * (double)v0.z + (double)a0.w * (double)v0.w +
                (double)a1.x * (double)v1.x + (double)a1.y * (double)v1.y +
                (double)a1.z * (double)v1.z + (double)a1.w * (double)v1.w;
    double s1 = (double)b0.x * (double)v0.x + (double)b0.y * (double)v0.y +
                (double)b0.z * (double)v0.z + (double)b0.w * (double)v0.w +
                (double)b1.x * (double)v1.x + (double)b1.y * (double)v1.y +
                (double)b1.z * (double)v1.z + (double)b1.w * (double)v1.w;
#pragma unroll
    for (int off = 1; off < 64; off <<= 1) {
      s0 += __shfl_xor(s0, off);
      s1 += __shfl_xor(s1, off);
    }
    if (lane == 0) {
      dsv[c0i] = s0 * ri * rinv[ci0];
      dsv[c1i] = s1 * ri * rinv[ci1];
    }
  }
  __syncthreads();

  if (t < NSEL) {
    const double v = dsv[t];
    const int id = sel[t];
    int rk = 0;
    for (int j = 0; j < NSEL; ++j)
      rk += (dsv[j] > v) || (dsv[j] == v && sel[j] < id);
    if (rk >= 1 && rk < KTOP) {
      nb[(size_t)i * NNB + (rk - 1)] = id;
      atomicAdd(&cnt_t[id], 1);
    }
  }
}

// ---- fallback: exact full scan for flagged rows (expected: none) ----
__global__ __launch_bounds__(256) void k_fallback(const float* __restrict__ x,
                                                  const double* __restrict__ rinv,
                                                  const int* __restrict__ flags,
                                                  int* __restrict__ nb,
                                                  int* __restrict__ cnt_t) {
  const int i = blockIdx.x;
  if (!flags[i]) return;
  const int t = threadIdx.x;
  __shared__ float xi[FEAT];
  __shared__ double cval[256];
  __shared__ double bestv[NNB];
  __shared__ int besti[NNB];
  for (int k = t; k < FEAT; k += 256) xi[k] = x[(size_t)i * FEAT + k];
  if (t < NNB) { bestv[t] = -1e300; besti[t] = 0x7fffffff; }
  __syncthreads();
  const double ri = rinv[i];
  for (int c0 = 0; c0 < N_NODES; c0 += 256) {
    const int c = c0 + t;
    double s = -1e300;
    if (c < N_NODES && c != i) {
      s = 0.0;
      for (int k = 0; k < FEAT; ++k) s += (double)xi[k] * (double)x[(size_t)c * FEAT + k];
      s *= ri * rinv[c];
    }
    cval[t] = s;
    __syncthreads();
    if (t == 0) {
      for (int j = 0; j < 256; ++j) {
        const int c2 = c0 + j;
        const double v = cval[j];
        if (v == -1e300) continue;
        int pos = NNB;
        for (int q = 0; q < NNB; ++q) {
          if (v > bestv[q] || (v == bestv[q] && c2 < besti[q])) { pos = q; break; }
        }
        if (pos < NNB) {
          for (int q = NNB - 1; q > pos; --q) { bestv[q] = bestv[q - 1]; besti[q] = besti[q - 1]; }
          bestv[pos] = v; besti[pos] = c2;
        }
      }
    }
    __syncthreads();
  }
  if (t < NNB) {
    nb[(size_t)i * NNB + t] = besti[t];
    atomicAdd(&cnt_t[besti[t]], 1);
  }
}

// -------------------- CSR build helpers --------------------
__global__ void k_zero3(int* __restrict__ a, int* __restrict__ b, int* __restrict__ c) {
  const int i = blockIdx.x * blockDim.x + threadIdx.x;
  if (i < N_NODES) { a[i] = 0; b[i] = 0; c[i] = 0; }
}

__global__ void k_count(const int* __restrict__ dsts, int ne, int* __restrict__ cnt) {
  const int e = blockIdx.x * blockDim.x + threadIdx.x;
  if (e < ne) atomicAdd(&cnt[dsts[e]], 1);
}

// both scans concurrently, wave-shfl based
__global__ void k_scan2(const int* __restrict__ cnt0, int* __restrict__ off0,
                        int* __restrict__ cur0, float* __restrict__ dinv0,
                        const int* __restrict__ cnt1, int* __restrict__ off1,
                        int* __restrict__ cur1, float* __restrict__ dinv1) {
  const int* cnt = blockIdx.x ? cnt1 : cnt0;
  int* off = blockIdx.x ? off1 : off0;
  int* cur = blockIdx.x ? cur1 : cur0;
  float* dinv = blockIdx.x ? dinv1 : dinv0;
  __shared__ int wsum[16];
  __shared__ int woff[16];
  __shared__ int base_s, tot_s;
  const int t = threadIdx.x;  // 1024
  const int lane = t & 63, wid = t >> 6;
  if (t == 0) base_s = 0;
  __syncthreads();
  for (int b0 = 0; b0 < N_NODES; b0 += 1024) {
    const int i = b0 + t;
    const int v = (i < N_NODES) ? cnt[i] : 0;
    int inc = v;
#pragma unroll
    for (int o = 1; o < 64; o <<= 1) {
      const int u = __shfl_up(inc, o, 64);
      if (lane >= o) inc += u;
    }
    if (lane == 63) wsum[wid] = inc;
    __syncthreads();
    if (wid == 0) {
      const int ws = (lane < 16) ? wsum[lane] : 0;
      int wi = ws;
#pragma unroll
      for (int o = 1; o < 16; o <<= 1) {
        const int u = __shfl_up(wi, o, 64);
        if (lane >= o) wi += u;
      }
      if (lane < 16) woff[lane] = wi - ws;
      if (lane == 15) tot_s = wi;
    }
    __syncthreads();
    if (i < N_NODES) {
      const int excl = base_s + woff[wid] + (inc - v);
      off[i] = excl;
      cur[i] = excl;
      dinv[i] = rsqrtf((float)(v + 1));
    }
    __syncthreads();
    if (t == 0) base_s += tot_s;
    __syncthreads();
  }
  if (t == 0) off[N_NODES] = base_s;
}

__global__ void k_scatter_s(const int* __restrict__ src, const int* __restrict__ dst, int ne,
                            int* __restrict__ cur, int* __restrict__ csr) {
  const int e = blockIdx.x * blockDim.x + threadIdx.x;
  if (e < ne) {
    const int p = atomicAdd(&cur[dst[e]], 1);
    csr[p] = src[e];
  }
}

__global__ void k_scatter_t(const int* __restrict__ nb, int* __restrict__ cur,
                            int* __restrict__ csr) {
  const int e = blockIdx.x * blockDim.x + threadIdx.x;
  if (e < N_NODES * NNB) {
    const int i = e / NNB;
    const int v = nb[e];
    const int p = atomicAdd(&cur[v], 1);
    csr[p] = i;
  }
}

// ---- f16 MFMA feature GEMM (merged pair), 3-stage ring, f16 out ----
__global__ __launch_bounds__(256) void k_fgemm2(const unsigned short* __restrict__ A0,
                                                const unsigned short* __restrict__ A1,
                                                const unsigned short* __restrict__ Bt0,
                                                const unsigned short* __restrict__ Bt1,
                                                unsigned short* __restrict__ C0,
                                                unsigned short* __restrict__ C1,
                                                int M, int K, int N) {
  __shared__ __align__(16) unsigned short As[3][4096];
  __shared__ __align__(16) unsigned short Bs[3][4096];
  const int t = threadIdx.x;
  const int lane = t & 63, w = t >> 6;
  const int lr = lane & 15, lk = lane >> 4;
  const int wr = (w >> 1) * 64, wc = (w & 1) * 64;
  const int nbn = N >> 7;
  const int half = blockIdx.y / nbn;
  const unsigned short* A = half ? A1 : A0;
  const unsigned short* Bt = half ? Bt1 : Bt0;
  unsigned short* C = half ? C1 : C0;
  const int arow0 = blockIdx.x * 128, bcol0 = (blockIdx.y % nbn) * 128;

  auto stage = [&](int s, int k0) {
#pragma unroll
    for (int it = 0; it < 2; ++it) {
      const int slot = it * 256 + w * 64 + lane;
      const int r = slot >> 2;
      const int qs = (slot & 3) ^ ((r >> 1) & 3);
      {
        const int gr = min(arow0 + r, M - 1);
        gload_lds16(A + (size_t)gr * K + k0 + qs * 8, &As[s][(it * 256 + w * 64) * 8]);
      }
      {
        const int gc = min(bcol0 + r, N - 1);
        gload_lds16(Bt + (size_t)gc * K + k0 + qs * 8, &Bs[s][(it * 256 + w * 64) * 8]);
      }
    }
  };

  f32x4 acc[4][4];
#pragma unroll
  for (int m = 0; m < 4; ++m)
#pragma unroll
    for (int n = 0; n < 4; ++n) acc[m][n] = (f32x4){0.f, 0.f, 0.f, 0.f};

  stage(0, 0);
  if (K > 32) stage(1, 32);

  const int NT = K >> 5;
  int cur = 0, nxt = 2;
  for (int kt = 0; kt < NT; ++kt) {
    if (kt + 2 < NT) {
      stage(nxt, (kt + 2) << 5);
      asm volatile("s_waitcnt vmcnt(8)" ::: "memory");
    } else if (kt + 1 < NT) {
      asm volatile("s_waitcnt vmcnt(4)" ::: "memory");
    } else {
      asm volatile("s_waitcnt vmcnt(0)" ::: "memory");
    }
    __builtin_amdgcn_sched_barrier(0);
    __builtin_amdgcn_s_barrier();
    const unsigned short* Ab = As[cur];
    const unsigned short* Bb = Bs[cur];
    short8 a[4], b[4];
#pragma unroll
    for (int m = 0; m < 4; ++m) {
      const int row = wr + m * 16 + lr;
      a[m] = *(const short8*)(Ab + (((row << 2) | (lk ^ ((row >> 1) & 3))) << 3));
    }
#pragma unroll
    for (int n = 0; n < 4; ++n) {
      const int row = wc + n * 16 + lr;
      b[n] = *(const short8*)(Bb + (((row << 2) | (lk ^ ((row >> 1) & 3))) << 3));
    }
    __builtin_amdgcn_s_setprio(1);
#pragma unroll
    for (int m = 0; m < 4; ++m)
#pragma unroll
      for (int n = 0; n < 4; ++n)
        acc[m][n] = __builtin_amdgcn_mfma_f32_16x16x32_f16(a[m], b[n], acc[m][n], 0, 0, 0);
    __builtin_amdgcn_s_setprio(0);
    asm volatile("" ::: "memory");
    if (kt + 1 < NT) __builtin_amdgcn_s_barrier();
    cur = (cur == 2) ? 0 : cur + 1;
    nxt = (nxt == 2) ? 0 : nxt + 1;
  }

#pragma unroll
  for (int m = 0; m < 4; ++m) {
    const int rb = arow0 + wr + m * 16 + lk * 4;
#pragma unroll
    for (int n = 0; n < 4; ++n) {
      const int gc = bcol0 + wc + n * 16 + lr;
#pragma unroll
      for (int q = 0; q < 4; ++q) {
        const int gm = rb + q;
        if (gm < M) C[(size_t)gm * N + gc] = f2h(acc[m][n][q]);
      }
    }
  }
}

// ---- layer-1 aggregation, both branches in one launch (blockIdx.y) ----
__global__ void k_agg_h2(const unsigned short* __restrict__ h0,
                         const unsigned short* __restrict__ h1,
                         const float* __restrict__ bias0, const float* __restrict__ bias1,
                         const float* __restrict__ dinv0, const float* __restrict__ dinv1,
                         const int* __restrict__ off0, const int* __restrict__ off1,
                         const int* __restrict__ csr0, const int* __restrict__ csr1,
                         unsigned short* __restrict__ out0, unsigned short* __restrict__ out1) {
  const int br = blockIdx.y;
  const unsigned short* h = br ? h1 : h0;
  const float* bias = br ? bias1 : bias0;
  const float* dinv = br ? dinv1 : dinv0;
  const int* off = br ? off1 : off0;
  const int* csr = br ? csr1 : csr0;
  unsigned short* out = br ? out1 : out0;
  const int v = blockIdx.x;
  const int c = threadIdx.x;  // HID
  const float dv = dinv[v];
  float acc = h2f(h[(size_t)v * HID + c]) * dv;
  const int s0 = off[v], s1 = off[v + 1];
  int e = s0;
  for (; e + 1 < s1; e += 2) {
    const int sa = csr[e], sb = csr[e + 1];
    const float ha = h2f(h[(size_t)sa * HID + c]), hb = h2f(h[(size_t)sb * HID + c]);
    acc += ha * dinv[sa] + hb * dinv[sb];
  }
  if (e < s1) {
    const int sa = csr[e];
    acc += h2f(h[(size_t)sa * HID + c]) * dinv[sa];
  }
  acc = acc * dv + bias[c];
  out[(size_t)v * HID + c] = f2h(fmaxf(acc, 0.f));
}

// ---- layer-2 aggregation (both branches) + fusion + Student-t, fused ----
__global__ void k_aggfuse(const unsigned short* __restrict__ h2_s,
                          const unsigned short* __restrict__ h2_t,
                          const float* __restrict__ b_s2, const float* __restrict__ b_t2,
                          const float* __restrict__ dinv_s, const int* __restrict__ off_s,
                          const int* __restrict__ csr_s, const float* __restrict__ dinv_t,
                          const int* __restrict__ off_t, const int* __restrict__ csr_t,
                          const float* __restrict__ fw, const float* __restrict__ cent,
                          float* __restrict__ out_z, float* __restrict__ out_q) {
  const int v = blockIdx.x;
  const int c = threadIdx.x;  // 128
  __shared__ float zsh[EMB];
  __shared__ float cs[NC][EMB];
  __shared__ float qv[NC];
  __shared__ float qs;
  for (int k = c; k < NC * EMB; k += 128) ((float*)cs)[k] = cent[k];
  float zs, zt;
  {
    const float dv = dinv_s[v];
    float acc = h2f(h2_s[(size_t)v * EMB + c]) * dv;
    const int s0 = off_s[v], s1 = off_s[v + 1];
    int e = s0;
    for (; e + 1 < s1; e += 2) {
      const int sa = csr_s[e], sb = csr_s[e + 1];
      acc += h2f(h2_s[(size_t)sa * EMB + c]) * dinv_s[sa] +
             h2f(h2_s[(size_t)sb * EMB + c]) * dinv_s[sb];
    }
    if (e < s1) {
      const int sa = csr_s[e];
      acc += h2f(h2_s[(size_t)sa * EMB + c]) * dinv_s[sa];
    }
    zs = acc * dv + b_s2[c];
  }
  {
    const float dv = dinv_t[v];
    float acc = h2f(h2_t[(size_t)v * EMB + c]) * dv;
    const int s0 = off_t[v], s1 = off_t[v + 1];
    int e = s0;
    for (; e + 1 < s1; e += 2) {
      const int sa = csr_t[e], sb = csr_t[e + 1];
      acc += h2f(h2_t[(size_t)sa * EMB + c]) * dinv_t[sa] +
             h2f(h2_t[(size_t)sb * EMB + c]) * dinv_t[sb];
    }
    if (e < s1) {
      const int sa = csr_t[e];
      acc += h2f(h2_t[(size_t)sa * EMB + c]) * dinv_t[sa];
    }
    zt = acc * dv + b_t2[c];
  }
  const float beta = 1.f / (1.f + expf(-fw[0]));
  const float z = beta * zs + (1.f - beta) * zt;
  out_z[(size_t)v * EMB + c] = z;
  zsh[c] = z;
  __syncthreads();
  if (c < NC) {
    float s = 0.f;
    for (int k = 0; k < EMB; ++k) {
      const float d = zsh[k] - cs[c][k];
      s += d * d;
    }
    qv[c] = 1.f / (1.f + s);
  }
  __syncthreads();
  if (c == 0) {
    float s = 0.f;
    for (int k = 0; k < NC; ++k) s += qv[k];
    qs = s;
  }
  __syncthreads();
  if (c < NC) out_q[(size_t)v * NC + c] = qv[c] / qs;
}

extern "C" void kernel_launch(void* const* d_in, const int* in_sizes, int n_in, void* d_out,
                              int out_size, void* d_ws, size_t ws_size, hipStream_t stream) {
  const float* x = (const float*)d_in[0];
  const int* ei = (const int*)d_in[1];
  const float* W_s1 = (const float*)d_in[2];
  const float* b_s1 = (const float*)d_in[3];
  const float* W_s2 = (const float*)d_in[4];
  const float* b_s2 = (const float*)d_in[5];
  const float* W_t1 = (const float*)d_in[6];
  const float* b_t1 = (const float*)d_in[7];
  const float* W_t2 = (const float*)d_in[8];
  const float* b_t2 = (const float*)d_in[9];
  const float* fw = (const float*)d_in[10];
  const float* cent = (const float*)d_in[11];
  float* out_z = (float*)d_out;
  float* out_q = out_z + (size_t)N_NODES * EMB;

  char* w = (char*)d_ws;
  size_t o = 0;
  auto alloc = [&](size_t bytes) -> void* {
    void* p = w + o;
    o += (bytes + 255) & ~(size_t)255;
    return p;
  };
  // xn8 (K-blocked fp8, 5.12MB; region 10.24MB) -> h1_s f16 after simgemm
  unsigned char* xn8 = (unsigned char*)alloc((size_t)N_NODES * FEAT * 2);
  unsigned short* h1_s = (unsigned short*)xn8;
  // xf (raw f16) -> h2_s/h2_t f16 after layer-1 GEMMs
  unsigned short* xf = (unsigned short*)alloc((size_t)N_NODES * FEAT * 2);
  unsigned short* h2_s = xf;
  unsigned short* h2_t = xf + (size_t)N_NODES * EMB;
  double* rinv = (double*)alloc((size_t)N_NODES * 8);
  // cap_buf (5.12 MB) -> r1_s f16 after k_knn
  unsigned int* cap_buf = (unsigned int*)alloc((size_t)N_NODES * CAP * 4);
  unsigned short* r1_s = (unsigned short*)cap_buf;
  unsigned short* r1_t = (unsigned short*)alloc((size_t)N_NODES * HID * 2);
  unsigned short* h1_t = (unsigned short*)alloc((size_t)N_NODES * HID * 2);
  int* nb = (int*)alloc((size_t)N_NODES * NNB * 4);
  int* cnt_s = (int*)alloc((size_t)N_NODES * 4);
  int* off_s = (int*)alloc((size_t)(N_NODES + 1) * 4);
  int* cur_s = (int*)alloc((size_t)N_NODES * 4);
  float* dinv_s = (float*)alloc((size_t)N_NODES * 4);
  int* cnt_t = (int*)alloc((size_t)N_NODES * 4);
  int* off_t = (int*)alloc((size_t)(N_NODES + 1) * 4);
  int* cur_t = (int*)alloc((size_t)N_NODES * 4);
  float* dinv_t = (float*)alloc((size_t)N_NODES * 4);
  int* csr_s = (int*)alloc((size_t)NE_EDGES * 4);
  int* csr_t = (int*)alloc((size_t)N_NODES * NNB * 4);
  int* cnt_row = (int*)alloc((size_t)N_NODES * 4);
  int* flags = (int*)alloc((size_t)N_NODES * 4);
  unsigned short* Wt_s1 = (unsigned short*)alloc((size_t)FEAT * HID * 2);
  unsigned short* Wt_t1 = (unsigned short*)alloc((size_t)FEAT * HID * 2);
  unsigned short* Wt_s2 = (unsigned short*)alloc((size_t)HID * EMB * 2);
  unsigned short* Wt_t2 = (unsigned short*)alloc((size_t)HID * EMB * 2);

  const int* e_src = ei;
  const int* e_dst = ei + NE_EDGES;

  // 1. norms (K-blocked fp8 + f16 raw) + all weight transposes
  k_norms<<<N_NODES, 128, 0, stream>>>(x, xn8, xf, rinv);
  {
    const int tot = 2 * FEAT * HID + 2 * HID * EMB;
    k_wtall<<<(tot + 255) / 256, 256, 0, stream>>>(W_s1, W_t1, W_s2, W_t2, Wt_s1, Wt_t1, Wt_s2,
                                                   Wt_t2);
  }
  // 2. zero counters + structural degrees
  k_zero3<<<(N_NODES + 255) / 256, 256, 0, stream>>>(cnt_s, cnt_t, cnt_row);
  k_count<<<(NE_EDGES + 255) / 256, 256, 0, stream>>>(e_dst, NE_EDGES, cnt_s);
  // 3. sim GEMM (128^2 upper triangle, fp8 K-blocked, 2-stage/4 blk/CU) + filter
  k_simgemm<<<NPAIR, 256, 0, stream>>>(xn8, cap_buf, cnt_row);
  // 4. select + f64 rescore (+ topology degree counting); fallback net
  k_knn<<<N_NODES, 256, 0, stream>>>(x, rinv, cap_buf, cnt_row, nb, flags, cnt_t);
  k_fallback<<<N_NODES, 256, 0, stream>>>(x, rinv, flags, nb, cnt_t);
  // 5. both scans + scatters
  k_scan2<<<2, 1024, 0, stream>>>(cnt_s, off_s, cur_s, dinv_s, cnt_t, off_t, cur_t, dinv_t);
  k_scatter_s<<<(NE_EDGES + 255) / 256, 256, 0, stream>>>(e_src, e_dst, NE_EDGES, cur_s, csr_s);
  k_scatter_t<<<(N_NODES * NNB + 255) / 256, 256, 0, stream>>>(nb, cur_t, csr_t);
  // 6. layer-1 GEMMs (h1_s aliases xn8: safe, simgemm done)
  {
    dim3 g1(NTB, 2 * (HID / 128));
    k_fgemm2<<<g1, 256, 0, stream>>>(xf, xf, Wt_s1, Wt_t1, h1_s, h1_t, N_NODES, FEAT, HID);
  }
  // 7. layer-1 aggregation, both branches (r1_s overwrites cap_buf: safe, k_knn done)
  {
    dim3 ga(N_NODES, 2);
    k_agg_h2<<<ga, HID, 0, stream>>>(h1_s, h1_t, b_s1, b_t1, dinv_s, dinv_t, off_s, off_t, csr_s,
                                     csr_t, r1_s, r1_t);
  }
  // 8. layer-2 GEMMs (h2_s/h2_t alias xf: safe, layer-1 done)
  {
    dim3 g2(NTB, 2 * (EMB / 128));
    k_fgemm2<<<g2, 256, 0, stream>>>(r1_s, r1_t, Wt_s2, Wt_t2, h2_s, h2_t, N_NODES, HID, EMB);
  }
  // 9. layer-2 aggregation + fusion + soft assignment (fused)
  k_aggfuse<<<N_NODES, EMB, 0, stream>>>(h2_s, h2_t, b_s2, b_t2, dinv_s, off_s, csr_s, dinv_t,
                                         off_t, csr_t, fw, cent, out_z, out_q);
}